// Round 4
// baseline (104.046 us; speedup 1.0000x reference)
//
#include <hip/hip_runtime.h>
#include <hip/hip_bf16.h>

// TripletLoss, N=384 pts, D=512, embeddings FP32, labels int32, loss out FP32 scalar.
// loss = sum_a sum_{p in pos(a)} sum_{n in neg(a)} relu(d(a,p)-d(a,n)+1) / num_valid
// pos includes the diagonal (p==a, d=0). num_valid = sum_a c_a*(N-c_a).
//
// Round-3 post-mortem: inputs are fp32 (per reference), NOT bf16. Reading fp32
// as packed bf16 made every off-diag distance Inf -> all triplet terms
// fmaxf(NaN,0)=0 -> loss computed as exactly 0 every round. Fixed: float4 loads.

#define NPTS 384
#define DIM  512
#define NTHR 384

__global__ void ws_init(float* ws_sum, unsigned long long* ws_cnt) {
    *ws_sum = 0.0f;
    *ws_cnt = 0ull;
}

__global__ __launch_bounds__(NTHR) void triplet_accum(
    const float* __restrict__ X,         // fp32 [NPTS][DIM]
    const int* __restrict__ labels,      // NPTS
    float* __restrict__ ws_sum,
    unsigned long long* __restrict__ ws_cnt)
{
    __shared__ float4 s_xa[DIM / 4];     // anchor row (2 KiB)
    __shared__ float s_d[NPTS];          // distance row
    __shared__ int   s_lab[NPTS];
    __shared__ float s_dp[NPTS];         // compacted positive distances
    __shared__ float s_dn[NPTS];         // compacted negative distances
    __shared__ int   s_np, s_nn;
    __shared__ float s_wred[NTHR / 64];

    const int t = threadIdx.x;
    const int a = blockIdx.x;

    if (t < DIM / 4) s_xa[t] = reinterpret_cast<const float4*>(X)[a * (DIM / 4) + t];
    s_lab[t] = labels[t];                // NTHR == NPTS
    if (t == 0) { s_np = 0; s_nn = 0; }
    __syncthreads();

    // ---- distance d(a, t): fp32 sum of squared diffs ----
    {
        const float4* xr = reinterpret_cast<const float4*>(X) + (size_t)t * (DIM / 4);
        float acc = 0.f;
#pragma unroll 8
        for (int k = 0; k < DIM / 4; ++k) {
            float4 vj = xr[k];
            float4 va = s_xa[k];         // wave-uniform -> LDS broadcast, no conflicts
            float d;
            d = vj.x - va.x; acc = fmaf(d, d, acc);
            d = vj.y - va.y; acc = fmaf(d, d, acc);
            d = vj.z - va.z; acc = fmaf(d, d, acc);
            d = vj.w - va.w; acc = fmaf(d, d, acc);
        }
        s_d[t] = sqrtf(acc);             // diagonal: exactly 0
    }
    __syncthreads();

    // ---- compact positives / negatives for this anchor ----
    {
        const int lab_a = s_lab[a];
        const float dv = s_d[t];
        if (s_lab[t] == lab_a) {
            int i = atomicAdd(&s_np, 1);
            s_dp[i] = dv;
        } else {
            int i = atomicAdd(&s_nn, 1);
            s_dn[i] = dv;
        }
    }
    __syncthreads();

    const int np = s_np, nn = s_nn;

    // ---- pair sum: relu(dp - dn + margin) over np*nn pairs ----
    float local = 0.f;
    for (int p = 0; p < np; ++p) {
        const float c = s_dp[p] + 1.0f;  // MARGIN = 1.0
        for (int n = t; n < nn; n += NTHR) {
            float v = c - s_dn[n];
            local += (v > 0.f) ? v : 0.f;   // NaN-propagating relu (no fmax NaN-swallow)
        }
    }

    // ---- block reduce ----
    for (int off = 32; off; off >>= 1) local += __shfl_down(local, off, 64);
    if ((t & 63) == 0) s_wred[t >> 6] = local;
    __syncthreads();

    if (t == 0) {
        float bs = 0.f;
        for (int w = 0; w < NTHR / 64; ++w) bs += s_wred[w];
        atomicAdd(ws_sum, bs);                                        // device-scope
        atomicAdd(ws_cnt, (unsigned long long)np * (unsigned long long)nn);
    }
}

__global__ void ws_finalize(const float* ws_sum, const unsigned long long* ws_cnt,
                            float* out) {
    double loss = (double)(*ws_sum) / ((double)(*ws_cnt) + 1e-16);
    *out = (float)loss;                  // fp32 output (reference dtype)
}

extern "C" void kernel_launch(void* const* d_in, const int* in_sizes, int n_in,
                              void* d_out, int out_size, void* d_ws, size_t ws_size,
                              hipStream_t stream) {
    (void)in_sizes; (void)n_in; (void)out_size; (void)ws_size;
    const float* X = (const float*)d_in[0];                // fp32 embeddings
    const int* labels = (const int*)d_in[1];

    float* ws_sum = (float*)d_ws;
    unsigned long long* ws_cnt = (unsigned long long*)((char*)d_ws + 8);

    ws_init<<<dim3(1), dim3(1), 0, stream>>>(ws_sum, ws_cnt);
    triplet_accum<<<dim3(NPTS), dim3(NTHR), 0, stream>>>(X, labels, ws_sum, ws_cnt);
    ws_finalize<<<dim3(1), dim3(1), 0, stream>>>(ws_sum, ws_cnt, (float*)d_out);
}

// Round 5
// 100.350 us; speedup vs baseline: 1.0368x; 1.0368x over previous
//
#include <hip/hip_runtime.h>
#include <hip/hip_bf16.h>

// TripletLoss, N=384, D=512, fp32 in, int labels, fp32 scalar out.
// loss = sum_a sum_p sum_n relu(d(a,p)-d(a,n)+1) / num_valid  (diag counts as pos)
//
// R4 post-mortem: 50us main kernel was address-divergence bound (64 lanes x 64
// distinct cachelines per load). R5: wave-per-row coalesced loads, anchor frags
// in registers, 2 anchors/block (halve X re-read), 2 kernels (no ws_init).

#define NPTS 384
#define DIM  512
#define NTHR 384
#define NBLK (NPTS / 2)   // 2 anchors per block

__global__ __launch_bounds__(NTHR) void triplet_rows(
    const float* __restrict__ X,         // fp32 [NPTS][DIM]
    const int* __restrict__ labels,      // NPTS
    float* __restrict__ psum,            // [NPTS] per-anchor pair-sum (plain stores)
    unsigned* __restrict__ pcnt)         // [NPTS] per-anchor np*nn
{
    __shared__ float s_d[2][NPTS];       // distance rows for both anchors
    __shared__ int   s_lab[NPTS];
    __shared__ float s_dp[NPTS];
    __shared__ float s_dn[NPTS];
    __shared__ int   s_np, s_nn;
    __shared__ float s_wred[NTHR / 64];

    const int t    = threadIdx.x;
    const int lane = t & 63;
    const int wv   = t >> 6;             // 0..5
    const int a0   = blockIdx.x * 2;

    s_lab[t] = labels[t];

    // Anchor fragments in registers: lane holds floats [lane*4, lane*4+4) and
    // [256+lane*4, ...) of each anchor row — same k-slice as the j-row loads.
    const float4* X4 = reinterpret_cast<const float4*>(X);
    const float4 fa00 = X4[(size_t)a0 * 128 + lane];
    const float4 fa01 = X4[(size_t)a0 * 128 + 64 + lane];
    const float4 fa10 = X4[(size_t)(a0 + 1) * 128 + lane];
    const float4 fa11 = X4[(size_t)(a0 + 1) * 128 + 64 + lane];

    // ---- phase 1: wave wv computes d(a0,j), d(a1,j) for j in [wv*64, wv*64+64)
    for (int i = 0; i < 64; ++i) {
        const int j = wv * 64 + i;
        const float4 v0 = X4[(size_t)j * 128 + lane];        // 1KB coalesced
        const float4 v1 = X4[(size_t)j * 128 + 64 + lane];   // 1KB coalesced
        float d, p0 = 0.f, p1 = 0.f;
        d = v0.x - fa00.x; p0 = fmaf(d, d, p0);
        d = v0.y - fa00.y; p0 = fmaf(d, d, p0);
        d = v0.z - fa00.z; p0 = fmaf(d, d, p0);
        d = v0.w - fa00.w; p0 = fmaf(d, d, p0);
        d = v1.x - fa01.x; p0 = fmaf(d, d, p0);
        d = v1.y - fa01.y; p0 = fmaf(d, d, p0);
        d = v1.z - fa01.z; p0 = fmaf(d, d, p0);
        d = v1.w - fa01.w; p0 = fmaf(d, d, p0);
        d = v0.x - fa10.x; p1 = fmaf(d, d, p1);
        d = v0.y - fa10.y; p1 = fmaf(d, d, p1);
        d = v0.z - fa10.z; p1 = fmaf(d, d, p1);
        d = v0.w - fa10.w; p1 = fmaf(d, d, p1);
        d = v1.x - fa11.x; p1 = fmaf(d, d, p1);
        d = v1.y - fa11.y; p1 = fmaf(d, d, p1);
        d = v1.z - fa11.z; p1 = fmaf(d, d, p1);
        d = v1.w - fa11.w; p1 = fmaf(d, d, p1);
        // 64-lane butterfly reduce (both anchors)
        for (int off = 32; off; off >>= 1) {
            p0 += __shfl_xor(p0, off, 64);
            p1 += __shfl_xor(p1, off, 64);
        }
        if (lane == 0) {
            s_d[0][j] = sqrtf(p0);       // diagonal j==a: exactly 0
            s_d[1][j] = sqrtf(p1);
        }
    }
    __syncthreads();

    // ---- phase 2: per-anchor compaction + pair sum ----
    for (int ai = 0; ai < 2; ++ai) {
        const int ga = a0 + ai;
        if (t == 0) { s_np = 0; s_nn = 0; }
        __syncthreads();

        const int lab_a = s_lab[ga];
        const float dv = s_d[ai][t];
        if (s_lab[t] == lab_a) {
            s_dp[atomicAdd(&s_np, 1)] = dv;
        } else {
            s_dn[atomicAdd(&s_nn, 1)] = dv;
        }
        __syncthreads();

        const int np = s_np, nn = s_nn;
        float local = 0.f;
        for (int p = 0; p < np; ++p) {
            const float c = s_dp[p] + 1.0f;      // MARGIN
            for (int n = t; n < nn; n += NTHR) {
                const float v = c - s_dn[n];
                local += (v > 0.f) ? v : 0.f;
            }
        }
        for (int off = 32; off; off >>= 1) local += __shfl_down(local, off, 64);
        if ((t & 63) == 0) s_wred[t >> 6] = local;
        __syncthreads();

        if (t == 0) {
            float bs = 0.f;
            for (int w = 0; w < NTHR / 64; ++w) bs += s_wred[w];
            psum[ga] = bs;                               // plain store, slot unique
            pcnt[ga] = (unsigned)(np * nn);
        }
        __syncthreads();                 // protect s_wred / s_np for next pass
    }
}

__global__ __launch_bounds__(NTHR) void reduce_final(
    const float* __restrict__ psum, const unsigned* __restrict__ pcnt,
    float* __restrict__ out)
{
    __shared__ float s_s[NTHR / 64];
    __shared__ unsigned long long s_c[NTHR / 64];
    const int t = threadIdx.x;
    float s = psum[t];
    unsigned long long c = (unsigned long long)pcnt[t];
    for (int off = 32; off; off >>= 1) {
        s += __shfl_down(s, off, 64);
        c += __shfl_down(c, off, 64);
    }
    if ((t & 63) == 0) { s_s[t >> 6] = s; s_c[t >> 6] = c; }
    __syncthreads();
    if (t == 0) {
        float ts = 0.f; unsigned long long tc = 0ull;
        for (int w = 0; w < NTHR / 64; ++w) { ts += s_s[w]; tc += s_c[w]; }
        double loss = (double)ts / ((double)tc + 1e-16);
        *out = (float)loss;              // fp32 output
    }
}

extern "C" void kernel_launch(void* const* d_in, const int* in_sizes, int n_in,
                              void* d_out, int out_size, void* d_ws, size_t ws_size,
                              hipStream_t stream) {
    (void)in_sizes; (void)n_in; (void)out_size; (void)ws_size;
    const float* X = (const float*)d_in[0];
    const int* labels = (const int*)d_in[1];

    float* psum = (float*)d_ws;                          // 384 floats
    unsigned* pcnt = (unsigned*)((char*)d_ws + NPTS * sizeof(float));

    triplet_rows<<<dim3(NBLK), dim3(NTHR), 0, stream>>>(X, labels, psum, pcnt);
    reduce_final<<<dim3(1), dim3(NTHR), 0, stream>>>(psum, pcnt, (float*)d_out);
}

// Round 6
// 75.394 us; speedup vs baseline: 1.3800x; 1.3310x over previous
//
#include <hip/hip_runtime.h>

// TripletLoss, N=384, D=512, fp32 in, int labels, fp32 scalar out.
// loss = sum_a sum_p sum_n relu(d(a,p)-d(a,n)+1) / num_valid (diag counts as pos)
//
// R5 post-mortem: wave-per-j butterfly reduce was latency-bound (serial 6-level
// shfl chain per element, VGPR=24 -> no ILP, VALUBusy 18%). R6: GEMM-style
// register-tiled distance matrix (no cross-lane ops), ballot compaction
// (kills the 139k LDS-atomic conflicts), 3 kernels.

#define NPTS 384
#define DIM  512
#define TS   32          // C-tile 32x32
#define BK   64
#define PITCH 68         // BK+4 pad floats; 272B row pitch keeps float4 align
#define NT1  256
#define NT2  384

// ---------------- K1: distance matrix (GEMM-shaped, diff^2 form) ------------
__global__ __launch_bounds__(NT1) void dist_tile(const float* __restrict__ X,
                                                 float* __restrict__ D) {
    __shared__ float As[TS * PITCH];
    __shared__ float Bs[TS * PITCH];
    const int t  = threadIdx.x;
    const int tx = t & 15, ty = t >> 4;        // 16x16 thread grid, 2x2 per thread
    const int bi = blockIdx.y * TS;
    const int bj = blockIdx.x * TS;

    const float4* X4 = (const float4*)X;       // row pitch DIM/4 = 128 float4
    const int r0 = t >> 4, c4 = t & 15;        // staging: 32 rows x 16 float4

    float4 pa0, pa1, pb0, pb1;                 // register prefetch
    int k4 = 0;
    {   // stage tile 0
        pa0 = X4[(size_t)(bi + r0)      * (DIM/4) + k4 + c4];
        pa1 = X4[(size_t)(bi + r0 + 16) * (DIM/4) + k4 + c4];
        pb0 = X4[(size_t)(bj + r0)      * (DIM/4) + k4 + c4];
        pb1 = X4[(size_t)(bj + r0 + 16) * (DIM/4) + k4 + c4];
        *(float4*)&As[ r0       * PITCH + c4*4] = pa0;
        *(float4*)&As[(r0 + 16) * PITCH + c4*4] = pa1;
        *(float4*)&Bs[ r0       * PITCH + c4*4] = pb0;
        *(float4*)&Bs[(r0 + 16) * PITCH + c4*4] = pb1;
    }
    __syncthreads();

    float acc00 = 0.f, acc01 = 0.f, acc10 = 0.f, acc11 = 0.f;

    for (int kt = 0; kt < DIM / BK; ++kt) {
        if (kt < DIM / BK - 1) {               // prefetch next K-tile into regs
            k4 = (kt + 1) * (BK / 4);
            pa0 = X4[(size_t)(bi + r0)      * (DIM/4) + k4 + c4];
            pa1 = X4[(size_t)(bi + r0 + 16) * (DIM/4) + k4 + c4];
            pb0 = X4[(size_t)(bj + r0)      * (DIM/4) + k4 + c4];
            pb1 = X4[(size_t)(bj + r0 + 16) * (DIM/4) + k4 + c4];
        }
#pragma unroll
        for (int kk = 0; kk < BK / 4; ++kk) {
            const float4 a0 = *(const float4*)&As[(2*ty)   * PITCH + kk*4];
            const float4 a1 = *(const float4*)&As[(2*ty+1) * PITCH + kk*4];
            const float4 b0 = *(const float4*)&Bs[(2*tx)   * PITCH + kk*4];
            const float4 b1 = *(const float4*)&Bs[(2*tx+1) * PITCH + kk*4];
            float d;
            d = a0.x - b0.x; acc00 = fmaf(d, d, acc00);
            d = a0.y - b0.y; acc00 = fmaf(d, d, acc00);
            d = a0.z - b0.z; acc00 = fmaf(d, d, acc00);
            d = a0.w - b0.w; acc00 = fmaf(d, d, acc00);
            d = a0.x - b1.x; acc01 = fmaf(d, d, acc01);
            d = a0.y - b1.y; acc01 = fmaf(d, d, acc01);
            d = a0.z - b1.z; acc01 = fmaf(d, d, acc01);
            d = a0.w - b1.w; acc01 = fmaf(d, d, acc01);
            d = a1.x - b0.x; acc10 = fmaf(d, d, acc10);
            d = a1.y - b0.y; acc10 = fmaf(d, d, acc10);
            d = a1.z - b0.z; acc10 = fmaf(d, d, acc10);
            d = a1.w - b0.w; acc10 = fmaf(d, d, acc10);
            d = a1.x - b1.x; acc11 = fmaf(d, d, acc11);
            d = a1.y - b1.y; acc11 = fmaf(d, d, acc11);
            d = a1.z - b1.z; acc11 = fmaf(d, d, acc11);
            d = a1.w - b1.w; acc11 = fmaf(d, d, acc11);
        }
        __syncthreads();
        if (kt < DIM / BK - 1) {
            *(float4*)&As[ r0       * PITCH + c4*4] = pa0;
            *(float4*)&As[(r0 + 16) * PITCH + c4*4] = pa1;
            *(float4*)&Bs[ r0       * PITCH + c4*4] = pb0;
            *(float4*)&Bs[(r0 + 16) * PITCH + c4*4] = pb1;
            __syncthreads();
        }
    }

    // diagonal tiles load identical As/Bs rows -> i==j diffs exactly 0 -> d=0
    const int gi = bi + 2*ty, gj = bj + 2*tx;
    *(float2*)&D[(size_t)gi      * NPTS + gj] = make_float2(sqrtf(acc00), sqrtf(acc01));
    *(float2*)&D[(size_t)(gi+1)  * NPTS + gj] = make_float2(sqrtf(acc10), sqrtf(acc11));
}

// ---------------- K2: per-anchor compaction + pair sum ----------------------
__global__ __launch_bounds__(NT2) void pair_sums(const float* __restrict__ D,
                                                 const int* __restrict__ labels,
                                                 float* __restrict__ psum,
                                                 unsigned* __restrict__ pcnt) {
    __shared__ float s_dp[NPTS];
    __shared__ float s_dn[NPTS];
    __shared__ int   s_cp[NT2 / 64], s_cn[NT2 / 64];
    __shared__ float s_wred[NT2 / 64];

    const int t = threadIdx.x, lane = t & 63, w = t >> 6;
    const int a = blockIdx.x;
    const int lab_a = labels[a];

    const float dv  = D[(size_t)a * NPTS + t];
    const bool  isp = (labels[t] == lab_a);

    const unsigned long long m = __ballot(isp);
    if (lane == 0) { s_cp[w] = __popcll(m); s_cn[w] = 64 - __popcll(m); }
    __syncthreads();

    int basep = 0, basen = 0, np = 0, nn = 0;
#pragma unroll
    for (int i = 0; i < NT2 / 64; ++i) {
        if (i < w) { basep += s_cp[i]; basen += s_cn[i]; }
        np += s_cp[i]; nn += s_cn[i];
    }
    const unsigned long long blw = (1ull << lane) - 1ull;   // lane<64, safe
    if (isp) s_dp[basep + __popcll(m  & blw)] = dv;
    else     s_dn[basen + __popcll(~m & blw)] = dv;
    __syncthreads();

    float local = 0.f;
    for (int p = 0; p < np; ++p) {
        const float c = s_dp[p] + 1.0f;        // MARGIN
        for (int n = t; n < nn; n += NT2) {
            const float v = c - s_dn[n];
            local += (v > 0.f) ? v : 0.f;
        }
    }
    for (int off = 32; off; off >>= 1) local += __shfl_down(local, off, 64);
    if (lane == 0) s_wred[w] = local;
    __syncthreads();
    if (t == 0) {
        float bs = 0.f;
        for (int i = 0; i < NT2 / 64; ++i) bs += s_wred[i];
        psum[a] = bs;                          // unique slot, no init needed
        pcnt[a] = (unsigned)(np * nn);
    }
}

// ---------------- K3: final reduction -> fp32 scalar ------------------------
__global__ __launch_bounds__(NT2) void reduce_final(
    const float* __restrict__ psum, const unsigned* __restrict__ pcnt,
    float* __restrict__ out)
{
    __shared__ float s_s[NT2 / 64];
    __shared__ unsigned long long s_c[NT2 / 64];
    const int t = threadIdx.x;
    float s = psum[t];
    unsigned long long c = (unsigned long long)pcnt[t];
    for (int off = 32; off; off >>= 1) {
        s += __shfl_down(s, off, 64);
        c += __shfl_down(c, off, 64);
    }
    if ((t & 63) == 0) { s_s[t >> 6] = s; s_c[t >> 6] = c; }
    __syncthreads();
    if (t == 0) {
        float ts = 0.f; unsigned long long tc = 0ull;
        for (int w = 0; w < NT2 / 64; ++w) { ts += s_s[w]; tc += s_c[w]; }
        *out = (float)((double)ts / ((double)tc + 1e-16));
    }
}

extern "C" void kernel_launch(void* const* d_in, const int* in_sizes, int n_in,
                              void* d_out, int out_size, void* d_ws, size_t ws_size,
                              hipStream_t stream) {
    (void)in_sizes; (void)n_in; (void)out_size; (void)ws_size;
    const float* X = (const float*)d_in[0];
    const int* labels = (const int*)d_in[1];

    float*    Dmat = (float*)d_ws;                                   // 589824 B
    float*    psum = (float*)((char*)d_ws + (size_t)NPTS * NPTS * 4);
    unsigned* pcnt = (unsigned*)((char*)d_ws + (size_t)NPTS * NPTS * 4 + NPTS * 4);

    dist_tile  <<<dim3(NPTS / TS, NPTS / TS), dim3(NT1), 0, stream>>>(X, Dmat);
    pair_sums  <<<dim3(NPTS),                 dim3(NT2), 0, stream>>>(Dmat, labels, psum, pcnt);
    reduce_final<<<dim3(1),                   dim3(NT2), 0, stream>>>(psum, pcnt, (float*)d_out);
}